// Round 2
// baseline (142.429 us; speedup 1.0000x reference)
//
#include <hip/hip_runtime.h>

#define TLEN 524288
#define RCH 8      // rows per thread (chunk)
#define KH  12     // warm-up halo (truncation error ~0.25^12 worst-case)

typedef __fp16 half2v __attribute__((ext_vector_type(2)));

__device__ __forceinline__ unsigned packh2(float a, float b) {
  half2v h = __builtin_amdgcn_cvt_pkrtz(a, b);   // v_cvt_pkrtz_f16_f32
  return __builtin_bit_cast(unsigned, h);
}
__device__ __forceinline__ float2 unpackh2(unsigned u) {
  half2v h = __builtin_bit_cast(half2v, u);
  return make_float2((float)h.x, (float)h.y);
}

__device__ __forceinline__ float fastrcp(float x) {
  float r = __builtin_amdgcn_rcpf(x);
  r = r * (2.0f - x * r);   // one Newton step -> ~fp32 accurate
  return r;
}

__device__ __forceinline__ void load16(const float* __restrict__ p, float* __restrict__ m) {
  const float4* q = reinterpret_cast<const float4*>(p);
  float4 v0 = q[0], v1 = q[1], v2 = q[2], v3 = q[3];
  m[0]=v0.x; m[1]=v0.y; m[2]=v0.z; m[3]=v0.w;
  m[4]=v1.x; m[5]=v1.y; m[6]=v1.z; m[7]=v1.w;
  m[8]=v2.x; m[9]=v2.y; m[10]=v2.z; m[11]=v2.w;
  m[12]=v3.x; m[13]=v3.y; m[14]=v3.z; m[15]=v3.w;
}
__device__ __forceinline__ void load4(const float* __restrict__ p, float* __restrict__ v) {
  float4 t = *reinterpret_cast<const float4*>(p);
  v[0]=t.x; v[1]=t.y; v[2]=t.z; v[3]=t.w;
}

// o = a * b  (4x4 row-major)
__device__ __forceinline__ void mm4(float* __restrict__ o, const float* __restrict__ a,
                                    const float* __restrict__ b) {
#pragma unroll
  for (int i = 0; i < 4; ++i) {
#pragma unroll
    for (int j = 0; j < 4; ++j) {
      float acc = a[i*4+0] * b[0*4+j];
      acc = fmaf(a[i*4+1], b[1*4+j], acc);
      acc = fmaf(a[i*4+2], b[2*4+j], acc);
      acc = fmaf(a[i*4+3], b[3*4+j], acc);
      o[i*4+j] = acc;
    }
  }
}
// o = a * v  (4x4 * 4)
__device__ __forceinline__ void mv4(float* __restrict__ o, const float* __restrict__ a,
                                    const float* __restrict__ v) {
#pragma unroll
  for (int i = 0; i < 4; ++i) {
    float acc = a[i*4+0] * v[0];
    acc = fmaf(a[i*4+1], v[1], acc);
    acc = fmaf(a[i*4+2], v[2], acc);
    acc = fmaf(a[i*4+3], v[3], acc);
    o[i] = acc;
  }
}

// 4x4 inverse via adjugate (glm-style; layout-equivariant, no pivoting — diag dominant)
__device__ __forceinline__ void inv4(const float* __restrict__ m, float* __restrict__ inv) {
  float s0 = m[0]*m[5] - m[4]*m[1];
  float s1 = m[0]*m[6] - m[4]*m[2];
  float s2 = m[0]*m[7] - m[4]*m[3];
  float s3 = m[1]*m[6] - m[5]*m[2];
  float s4 = m[1]*m[7] - m[5]*m[3];
  float s5 = m[2]*m[7] - m[6]*m[3];
  float c5 = m[10]*m[15] - m[14]*m[11];
  float c4 = m[9]*m[15]  - m[13]*m[11];
  float c3 = m[9]*m[14]  - m[13]*m[10];
  float c2 = m[8]*m[15]  - m[12]*m[11];
  float c1 = m[8]*m[14]  - m[12]*m[10];
  float c0 = m[8]*m[13]  - m[12]*m[9];
  float det = s0*c5 - s1*c4 + s2*c3 + s3*c2 - s4*c1 + s5*c0;
  float r = fastrcp(det);
  inv[0]  = ( m[5]*c5 - m[6]*c4 + m[7]*c3) * r;
  inv[1]  = (-m[1]*c5 + m[2]*c4 - m[3]*c3) * r;
  inv[2]  = ( m[13]*s5 - m[14]*s4 + m[15]*s3) * r;
  inv[3]  = (-m[9]*s5 + m[10]*s4 - m[11]*s3) * r;
  inv[4]  = (-m[4]*c5 + m[6]*c2 - m[7]*c1) * r;
  inv[5]  = ( m[0]*c5 - m[2]*c2 + m[3]*c1) * r;
  inv[6]  = (-m[12]*s5 + m[14]*s2 - m[15]*s1) * r;
  inv[7]  = ( m[8]*s5 - m[10]*s2 + m[11]*s1) * r;
  inv[8]  = ( m[4]*c4 - m[5]*c2 + m[7]*c0) * r;
  inv[9]  = (-m[0]*c4 + m[1]*c2 - m[3]*c0) * r;
  inv[10] = ( m[12]*s4 - m[13]*s2 + m[15]*s0) * r;
  inv[11] = (-m[8]*s4 + m[9]*s2 - m[11]*s0) * r;
  inv[12] = (-m[4]*c3 + m[5]*c1 - m[6]*c0) * r;
  inv[13] = ( m[0]*c3 - m[1]*c1 + m[2]*c0) * r;
  inv[14] = (-m[12]*s3 + m[13]*s1 - m[14]*s0) * r;
  inv[15] = ( m[8]*s3 - m[9]*s1 + m[10]*s0) * r;
}

// forward elimination step at row t: carry (Bf,df) moves from t-1 to t.
// dB = Btilde - B[t], dd = dtilde - d[t] returned for storage.
__device__ __forceinline__ void fwd_step(int t, const float* __restrict__ Ag,
                                         const float* __restrict__ Bg,
                                         const float* __restrict__ Cg,
                                         const float* __restrict__ dg,
                                         float* __restrict__ Bf, float* __restrict__ df,
                                         float* __restrict__ dB, float* __restrict__ dd) {
  float Minv[16]; inv4(Bf, Minv);
  float At[16];  load16(Ag + (size_t)t * 16, At);
  float L[16];   mm4(L, At, Minv);                  // L = A_t * Btilde_{t-1}^{-1}
  float Ct[16];  load16(Cg + (size_t)(t - 1) * 16, Ct);
  float P[16];   mm4(P, L, Ct);                     // L * C_{t-1}
  float Bt[16];  load16(Bg + (size_t)t * 16, Bt);
  float dt[4];   load4(dg + (size_t)t * 4, dt);
  float q[4];    mv4(q, L, df);                     // L * dtilde_{t-1}
#pragma unroll
  for (int j = 0; j < 16; ++j) { dB[j] = -P[j]; Bf[j] = Bt[j] - P[j]; }
#pragma unroll
  for (int j = 0; j < 4; ++j)  { dd[j] = -q[j]; df[j] = dt[j] - q[j]; }
}

// backward (UL) elimination step at row t: carry (Bb,db) moves from t+1 to t.
__device__ __forceinline__ void bwd_step(int t, const float* __restrict__ Ag,
                                         const float* __restrict__ Bg,
                                         const float* __restrict__ Cg,
                                         const float* __restrict__ dg,
                                         float* __restrict__ Bb, float* __restrict__ db) {
  float Minv[16]; inv4(Bb, Minv);
  float Ct[16];  load16(Cg + (size_t)t * 16, Ct);
  float U[16];   mm4(U, Ct, Minv);                  // U = C_t * Bhat_{t+1}^{-1}
  float An[16];  load16(Ag + (size_t)(t + 1) * 16, An);
  float P[16];   mm4(P, U, An);                     // U * A_{t+1}
  float Bt[16];  load16(Bg + (size_t)t * 16, Bt);
  float dt[4];   load4(dg + (size_t)t * 4, dt);
  float q[4];    mv4(q, U, db);
#pragma unroll
  for (int j = 0; j < 16; ++j) Bb[j] = Bt[j] - P[j];
#pragma unroll
  for (int j = 0; j < 4; ++j)  db[j] = dt[j] - q[j];
}

__global__ __launch_bounds__(256) void btt_kernel(const float* __restrict__ Ag,
                                                  const float* __restrict__ Bg,
                                                  const float* __restrict__ Cg,
                                                  const float* __restrict__ dg,
                                                  float* __restrict__ xg) {
  const int chunk = blockIdx.x * 256 + threadIdx.x;
  const int s = chunk * RCH;
  const int e = s + RCH;

  // fp16-packed stored deltas for the R owned rows: dB=Btilde-B, dd=dtilde-d
  unsigned pB[RCH][8];
  unsigned pd[RCH][2];

  // ---------------- forward sweep (with left halo warm-up) ----------------
  {
    float Bf[16], df[4];
    int fs = s - KH; if (fs < 0) fs = 0;
    load16(Bg + (size_t)fs * 16, Bf);      // chain "start": exact when fs==0
    load4 (dg + (size_t)fs * 4,  df);
    for (int t = fs + 1; t < s; ++t) {     // warm-up (runtime trip count, no stores)
      float dB[16], dd[4];
      fwd_step(t, Ag, Bg, Cg, dg, Bf, df, dB, dd);
    }
#pragma unroll
    for (int i = 0; i < RCH; ++i) {        // fully unrolled -> static pB/pd indices
      const int t = s + i;
      float dB[16], dd[4];
      if (t == 0) {                         // row 0: Btilde=B, dtilde=d exactly
#pragma unroll
        for (int j = 0; j < 16; ++j) dB[j] = 0.0f;
#pragma unroll
        for (int j = 0; j < 4; ++j)  dd[j] = 0.0f;
      } else {
        fwd_step(t, Ag, Bg, Cg, dg, Bf, df, dB, dd);
      }
#pragma unroll
      for (int j = 0; j < 8; ++j) pB[i][j] = packh2(dB[2*j], dB[2*j+1]);
      pd[i][0] = packh2(dd[0], dd[1]);
      pd[i][1] = packh2(dd[2], dd[3]);
    }
  }

  // ------------- backward sweep (right halo warm-up) + combine -------------
  {
    float Bb[16], db[4];
    int bs = e - 1 + KH; if (bs > TLEN - 1) bs = TLEN - 1;
    load16(Bg + (size_t)bs * 16, Bb);      // chain "end": exact when bs==T-1
    load4 (dg + (size_t)bs * 4,  db);
    for (int t = bs - 1; t >= e; --t)      // warm-up
      bwd_step(t, Ag, Bg, Cg, dg, Bb, db);

    const bool lastIsBs = (bs == e - 1);   // only the final chunk (e == T)
#pragma unroll
    for (int i = RCH - 1; i >= 0; --i) {
      const int t = s + i;
      if (!(lastIsBs && i == RCH - 1))
        bwd_step(t, Ag, Bg, Cg, dg, Bb, db);
      // combine: (Btilde + Bhat - B) x = (dtilde + dhat - d)
      float Bc[16], dc[4];
#pragma unroll
      for (int j = 0; j < 8; ++j) {
        float2 u = unpackh2(pB[i][j]);
        Bc[2*j]   = Bb[2*j]   + u.x;
        Bc[2*j+1] = Bb[2*j+1] + u.y;
      }
      { float2 u = unpackh2(pd[i][0]); dc[0] = db[0] + u.x; dc[1] = db[1] + u.y; }
      { float2 u = unpackh2(pd[i][1]); dc[2] = db[2] + u.x; dc[3] = db[3] + u.y; }
      float Minv[16]; inv4(Bc, Minv);
      float xt[4];    mv4(xt, Minv, dc);
      *reinterpret_cast<float4*>(xg + (size_t)t * 4) =
          make_float4(xt[0], xt[1], xt[2], xt[3]);
    }
  }
}

extern "C" void kernel_launch(void* const* d_in, const int* in_sizes, int n_in,
                              void* d_out, int out_size, void* d_ws, size_t ws_size,
                              hipStream_t stream) {
  const float* A  = (const float*)d_in[0];
  const float* B  = (const float*)d_in[1];
  const float* C  = (const float*)d_in[2];
  const float* dv = (const float*)d_in[3];
  float* x = (float*)d_out;
  (void)in_sizes; (void)n_in; (void)d_ws; (void)ws_size; (void)out_size;

  const int nChunks = TLEN / RCH;          // 65536
  const int block = 256;
  const int grid = nChunks / block;        // 256
  btt_kernel<<<grid, block, 0, stream>>>(A, B, C, dv, x);
}

// Round 3
// 100.571 us; speedup vs baseline: 1.4162x; 1.4162x over previous
//
#include <hip/hip_runtime.h>

#define TLEN 524288
#define RCH 8        // rows per chunk
#define KH  6        // halo depth (init + 5 contraction steps; worst err ~3e-4)
#define NCH_BLK 128  // chunks per block (256 threads: 128 fwd + 128 bwd)

typedef __fp16 half2v __attribute__((ext_vector_type(2)));

__device__ __forceinline__ unsigned packh2(float a, float b) {
  half2v h = __builtin_amdgcn_cvt_pkrtz(a, b);
  return __builtin_bit_cast(unsigned, h);
}
__device__ __forceinline__ float2 unpackh2(unsigned u) {
  half2v h = __builtin_bit_cast(half2v, u);
  return make_float2((float)h.x, (float)h.y);
}

__device__ __forceinline__ float fastrcp(float x) {
  float r = __builtin_amdgcn_rcpf(x);
  r = r * (2.0f - x * r);
  return r;
}

__device__ __forceinline__ void load16(const float* __restrict__ p, float* __restrict__ m) {
  const float4* q = reinterpret_cast<const float4*>(p);
  float4 v0 = q[0], v1 = q[1], v2 = q[2], v3 = q[3];
  m[0]=v0.x; m[1]=v0.y; m[2]=v0.z; m[3]=v0.w;
  m[4]=v1.x; m[5]=v1.y; m[6]=v1.z; m[7]=v1.w;
  m[8]=v2.x; m[9]=v2.y; m[10]=v2.z; m[11]=v2.w;
  m[12]=v3.x; m[13]=v3.y; m[14]=v3.z; m[15]=v3.w;
}
__device__ __forceinline__ void load4(const float* __restrict__ p, float* __restrict__ v) {
  float4 t = *reinterpret_cast<const float4*>(p);
  v[0]=t.x; v[1]=t.y; v[2]=t.z; v[3]=t.w;
}

__device__ __forceinline__ void mm4(float* __restrict__ o, const float* __restrict__ a,
                                    const float* __restrict__ b) {
#pragma unroll
  for (int i = 0; i < 4; ++i) {
#pragma unroll
    for (int j = 0; j < 4; ++j) {
      float acc = a[i*4+0] * b[0*4+j];
      acc = fmaf(a[i*4+1], b[1*4+j], acc);
      acc = fmaf(a[i*4+2], b[2*4+j], acc);
      acc = fmaf(a[i*4+3], b[3*4+j], acc);
      o[i*4+j] = acc;
    }
  }
}
__device__ __forceinline__ void mv4(float* __restrict__ o, const float* __restrict__ a,
                                    const float* __restrict__ v) {
#pragma unroll
  for (int i = 0; i < 4; ++i) {
    float acc = a[i*4+0] * v[0];
    acc = fmaf(a[i*4+1], v[1], acc);
    acc = fmaf(a[i*4+2], v[2], acc);
    acc = fmaf(a[i*4+3], v[3], acc);
    o[i] = acc;
  }
}

// 4x4 inverse via adjugate (diag-dominant -> no pivoting)
__device__ __forceinline__ void inv4(const float* __restrict__ m, float* __restrict__ inv) {
  float s0 = m[0]*m[5] - m[4]*m[1];
  float s1 = m[0]*m[6] - m[4]*m[2];
  float s2 = m[0]*m[7] - m[4]*m[3];
  float s3 = m[1]*m[6] - m[5]*m[2];
  float s4 = m[1]*m[7] - m[5]*m[3];
  float s5 = m[2]*m[7] - m[6]*m[3];
  float c5 = m[10]*m[15] - m[14]*m[11];
  float c4 = m[9]*m[15]  - m[13]*m[11];
  float c3 = m[9]*m[14]  - m[13]*m[10];
  float c2 = m[8]*m[15]  - m[12]*m[11];
  float c1 = m[8]*m[14]  - m[12]*m[10];
  float c0 = m[8]*m[13]  - m[12]*m[9];
  float det = s0*c5 - s1*c4 + s2*c3 + s3*c2 - s4*c1 + s5*c0;
  float r = fastrcp(det);
  inv[0]  = ( m[5]*c5 - m[6]*c4 + m[7]*c3) * r;
  inv[1]  = (-m[1]*c5 + m[2]*c4 - m[3]*c3) * r;
  inv[2]  = ( m[13]*s5 - m[14]*s4 + m[15]*s3) * r;
  inv[3]  = (-m[9]*s5 + m[10]*s4 - m[11]*s3) * r;
  inv[4]  = (-m[4]*c5 + m[6]*c2 - m[7]*c1) * r;
  inv[5]  = ( m[0]*c5 - m[2]*c2 + m[3]*c1) * r;
  inv[6]  = (-m[12]*s5 + m[14]*s2 - m[15]*s1) * r;
  inv[7]  = ( m[8]*s5 - m[10]*s2 + m[11]*s1) * r;
  inv[8]  = ( m[4]*c4 - m[5]*c2 + m[7]*c0) * r;
  inv[9]  = (-m[0]*c4 + m[1]*c2 - m[3]*c0) * r;
  inv[10] = ( m[12]*s4 - m[13]*s2 + m[15]*s0) * r;
  inv[11] = (-m[8]*s4 + m[9]*s2 - m[11]*s0) * r;
  inv[12] = (-m[4]*c3 + m[5]*c1 - m[6]*c0) * r;
  inv[13] = ( m[0]*c3 - m[1]*c1 + m[2]*c0) * r;
  inv[14] = (-m[12]*s3 + m[13]*s1 - m[14]*s0) * r;
  inv[15] = ( m[8]*s3 - m[9]*s1 + m[10]*s0) * r;
}

// forward elimination step: carry (Bf,df) from t-1 to t; dB/dd = stored deltas
__device__ __forceinline__ void fwd_step(int t, const float* __restrict__ Ag,
                                         const float* __restrict__ Bg,
                                         const float* __restrict__ Cg,
                                         const float* __restrict__ dg,
                                         float* __restrict__ Bf, float* __restrict__ df,
                                         float* __restrict__ dB, float* __restrict__ dd) {
  float Minv[16]; inv4(Bf, Minv);
  float At[16];  load16(Ag + (size_t)t * 16, At);
  float L[16];   mm4(L, At, Minv);
  float Ct[16];  load16(Cg + (size_t)(t - 1) * 16, Ct);
  float P[16];   mm4(P, L, Ct);
  float Bt[16];  load16(Bg + (size_t)t * 16, Bt);
  float dt[4];   load4(dg + (size_t)t * 4, dt);
  float q[4];    mv4(q, L, df);
#pragma unroll
  for (int j = 0; j < 16; ++j) { dB[j] = -P[j]; Bf[j] = Bt[j] - P[j]; }
#pragma unroll
  for (int j = 0; j < 4; ++j)  { dd[j] = -q[j]; df[j] = dt[j] - q[j]; }
}

// backward (UL) elimination step: carry (Bb,db) from t+1 to t
__device__ __forceinline__ void bwd_step(int t, const float* __restrict__ Ag,
                                         const float* __restrict__ Bg,
                                         const float* __restrict__ Cg,
                                         const float* __restrict__ dg,
                                         float* __restrict__ Bb, float* __restrict__ db) {
  float Minv[16]; inv4(Bb, Minv);
  float Ct[16];  load16(Cg + (size_t)t * 16, Ct);
  float U[16];   mm4(U, Ct, Minv);
  float An[16];  load16(Ag + (size_t)(t + 1) * 16, An);
  float P[16];   mm4(P, U, An);
  float Bt[16];  load16(Bg + (size_t)t * 16, Bt);
  float dt[4];   load4(dg + (size_t)t * 4, dt);
  float q[4];    mv4(q, U, db);
#pragma unroll
  for (int j = 0; j < 16; ++j) Bb[j] = Bt[j] - P[j];
#pragma unroll
  for (int j = 0; j < 4; ++j)  db[j] = dt[j] - q[j];
}

// Role-split: threads 0..127 = fwd sweep for chunk lc, threads 128..255 = bwd+combine.
// Handoff of fp16-packed fwd deltas through LDS (stride 81 u32: 81%32=17, coprime
// with 32 banks -> 2-way aliasing only, free).
__global__ __launch_bounds__(256) void btt_kernel(const float* __restrict__ Ag,
                                                  const float* __restrict__ Bg,
                                                  const float* __restrict__ Cg,
                                                  const float* __restrict__ dg,
                                                  float* __restrict__ xg) {
  __shared__ unsigned lds_d[NCH_BLK][81];   // [chunk][row*10 + j], 80 used + 1 pad

  const int lc = threadIdx.x & (NCH_BLK - 1);
  const bool isFwd = threadIdx.x < NCH_BLK;          // wave-uniform (waves 0-1 vs 2-3)
  const int chunk = blockIdx.x * NCH_BLK + lc;
  const int s = chunk * RCH;
  const int e = s + RCH;

  if (isFwd) {
    // ---------------- forward sweep: halo warm-up + owned, deltas -> LDS ----------
    float Bf[16], df[4];
    int fs = s - KH; if (fs < 0) fs = 0;
    load16(Bg + (size_t)fs * 16, Bf);
    load4 (dg + (size_t)fs * 4,  df);
    for (int t = fs + 1; t < s; ++t) {               // halo (KH-1 steps)
      float dB[16], dd[4];
      fwd_step(t, Ag, Bg, Cg, dg, Bf, df, dB, dd);
    }
#pragma unroll
    for (int i = 0; i < RCH; ++i) {
      const int t = s + i;
      float dB[16], dd[4];
      if (t == 0) {
#pragma unroll
        for (int j = 0; j < 16; ++j) dB[j] = 0.0f;
#pragma unroll
        for (int j = 0; j < 4; ++j)  dd[j] = 0.0f;
      } else {
        fwd_step(t, Ag, Bg, Cg, dg, Bf, df, dB, dd);
      }
#pragma unroll
      for (int j = 0; j < 8; ++j) lds_d[lc][i*10 + j] = packh2(dB[2*j], dB[2*j+1]);
      lds_d[lc][i*10 + 8] = packh2(dd[0], dd[1]);
      lds_d[lc][i*10 + 9] = packh2(dd[2], dd[3]);
    }
    __syncthreads();                                 // publish deltas, then retire
  } else {
    // ---------------- backward sweep: halo warm-up, wait, owned + combine ---------
    float Bb[16], db[4];
    int bs = e - 1 + KH; if (bs > TLEN - 1) bs = TLEN - 1;
    load16(Bg + (size_t)bs * 16, Bb);
    load4 (dg + (size_t)bs * 4,  db);
    for (int t = bs - 1; t >= e; --t)                // halo
      bwd_step(t, Ag, Bg, Cg, dg, Bb, db);

    __syncthreads();                                 // fwd deltas now in LDS

    const bool lastIsBs = (bs == e - 1);             // only the final chunk
#pragma unroll
    for (int i = RCH - 1; i >= 0; --i) {
      const int t = s + i;
      if (!(lastIsBs && i == RCH - 1))
        bwd_step(t, Ag, Bg, Cg, dg, Bb, db);
      // combine: (Btilde + Bhat - B) x = (dtilde + dhat - d)
      float Bc[16], dc[4];
#pragma unroll
      for (int j = 0; j < 8; ++j) {
        float2 u = unpackh2(lds_d[lc][i*10 + j]);
        Bc[2*j]   = Bb[2*j]   + u.x;
        Bc[2*j+1] = Bb[2*j+1] + u.y;
      }
      { float2 u = unpackh2(lds_d[lc][i*10 + 8]); dc[0] = db[0] + u.x; dc[1] = db[1] + u.y; }
      { float2 u = unpackh2(lds_d[lc][i*10 + 9]); dc[2] = db[2] + u.x; dc[3] = db[3] + u.y; }
      float Minv[16]; inv4(Bc, Minv);
      float xt[4];    mv4(xt, Minv, dc);
      *reinterpret_cast<float4*>(xg + (size_t)t * 4) =
          make_float4(xt[0], xt[1], xt[2], xt[3]);
    }
  }
}

extern "C" void kernel_launch(void* const* d_in, const int* in_sizes, int n_in,
                              void* d_out, int out_size, void* d_ws, size_t ws_size,
                              hipStream_t stream) {
  const float* A  = (const float*)d_in[0];
  const float* B  = (const float*)d_in[1];
  const float* C  = (const float*)d_in[2];
  const float* dv = (const float*)d_in[3];
  float* x = (float*)d_out;
  (void)in_sizes; (void)n_in; (void)d_ws; (void)ws_size; (void)out_size;

  const int nChunks = TLEN / RCH;            // 65536
  const int grid = nChunks / NCH_BLK;        // 512 blocks x 256 threads (2 waves/SIMD)
  btt_kernel<<<grid, 256, 0, stream>>>(A, B, C, dv, x);
}